// Round 1
// 611.102 us; speedup vs baseline: 1.1710x; 1.1710x over previous
//
#include <hip/hip_runtime.h>
#include <math.h>

#define VOL (256 * 256 * 256)
#define NSHELL 222
#define SBINS 224
#define NSPLIT 16
#define PI_D 3.14159265358979323846
#define VSTRIDE ((size_t)129 << 16)   // one half-volume: 129 planes of 256x256 float2

// base-4 digit reversal of an 8-bit index (self-inverse) -- used by pass 1 only
__device__ __forceinline__ int rev4(int e) {
  return ((e & 3) << 6) | (((e >> 2) & 3) << 4) | (((e >> 4) & 3) << 2) | ((e >> 6) & 3);
}

// one-time twiddle table: gtw[k] = exp(-2*pi*i*k/256), f64-accurate
__global__ void tw_init(float2* __restrict__ gtw) {
  int t = threadIdx.x;
  double a = -2.0 * PI_D * (double)t / 256.0;
  gtw[t] = make_float2((float)cos(a), (float)sin(a));
}

// radix-4 DIF butterfly on 4 LDS slots (pass 1 only)
__device__ __forceinline__ void bfly4_dif(float* re, float* im, const float* twr,
                                          const float* twi, int a0, int a1, int a2,
                                          int a3, int t1, int t2, int t3) {
  float x0r = re[a0], x0i = im[a0], x1r = re[a1], x1i = im[a1];
  float x2r = re[a2], x2i = im[a2], x3r = re[a3], x3i = im[a3];
  float s02r = x0r + x2r, s02i = x0i + x2i, d02r = x0r - x2r, d02i = x0i - x2i;
  float s13r = x1r + x3r, s13i = x1i + x3i, d13r = x1r - x3r, d13i = x1i - x3i;
  re[a0] = s02r + s13r; im[a0] = s02i + s13i;
  float c1r = d02r + d13i, c1i = d02i - d13r;
  re[a1] = c1r * twr[t1] - c1i * twi[t1]; im[a1] = c1r * twi[t1] + c1i * twr[t1];
  float c2r = s02r - s13r, c2i = s02i - s13i;
  re[a2] = c2r * twr[t2] - c2i * twi[t2]; im[a2] = c2r * twi[t2] + c2i * twr[t2];
  float c3r = d02r - d13i, c3i = d02i + d13r;
  re[a3] = c3r * twr[t3] - c3i * twi[t3]; im[a3] = c3r * twi[t3] + c3i * twr[t3];
}

// wave-level segmented reduce + flush: bins nondecreasing across lanes.
__device__ __forceinline__ void seg_flush(float* sh, int sb, float nv, float pv,
                                          float qv, int l) {
#pragma unroll
  for (int d = 1; d < 64; d <<= 1) {
    int sbo = __shfl_down(sb, d);
    float no = __shfl_down(nv, d);
    float po = __shfl_down(pv, d);
    float qo = __shfl_down(qv, d);
    if (l + d < 64 && sbo == sb) { nv += no; pv += po; qv += qo; }
  }
  int sbp = __shfl_up(sb, 1);
  if (l == 0 || sbp != sb) {
    atomicAdd(&sh[3 * sb + 0], nv);
    atomicAdd(&sh[3 * sb + 1], pv);
    atomicAdd(&sh[3 * sb + 2], qv);
  }
}

__device__ __forceinline__ float2 cmul(float2 a, float2 b) {
  return make_float2(a.x * b.x - a.y * b.y, a.x * b.y + a.y * b.x);
}

// in-register 16-point DFT, natural-order in and out.
// X[k] = sum_j x[j] * W16^(j*k), W16 = exp(-2*pi*i/16).
__device__ __forceinline__ void fft16(float2* v) {
  const float C1 = 0.92387953251128674f;   // cos(pi/8)
  const float S1 = 0.38268343236508978f;   // sin(pi/8)
  const float R2 = 0.70710678118654752f;   // sqrt(2)/2
  float2 s[16];
  // stage 1: radix-4 over the high input digit; s[4r+p] = B_p[r] * W16^(p*r)
#pragma unroll
  for (int p = 0; p < 4; ++p) {
    float2 a = v[p], b = v[p + 4], cc = v[p + 8], d = v[p + 12];
    float2 t0 = make_float2(a.x + cc.x, a.y + cc.y);
    float2 t2 = make_float2(a.x - cc.x, a.y - cc.y);
    float2 t1 = make_float2(b.x + d.x, b.y + d.y);
    float2 t3 = make_float2(b.x - d.x, b.y - d.y);
    s[p]      = make_float2(t0.x + t1.x, t0.y + t1.y);   // r=0
    s[p + 4]  = make_float2(t2.x + t3.y, t2.y - t3.x);   // r=1: t2 - i*t3
    s[p + 8]  = make_float2(t0.x - t1.x, t0.y - t1.y);   // r=2
    s[p + 12] = make_float2(t2.x - t3.y, t2.y + t3.x);   // r=3: t2 + i*t3
  }
  s[5]  = cmul(s[5],  make_float2(C1, -S1));    // W16^1
  s[6]  = cmul(s[6],  make_float2(R2, -R2));    // W16^2
  s[7]  = cmul(s[7],  make_float2(S1, -C1));    // W16^3
  s[9]  = cmul(s[9],  make_float2(R2, -R2));    // W16^2
  s[10] = cmul(s[10], make_float2(0.f, -1.f));  // W16^4
  s[11] = cmul(s[11], make_float2(-R2, -R2));   // W16^6
  s[13] = cmul(s[13], make_float2(S1, -C1));    // W16^3
  s[14] = cmul(s[14], make_float2(-R2, -R2));   // W16^6
  s[15] = cmul(s[15], make_float2(-C1, S1));    // W16^9
  // stage 2: FFT-4 over p within each group r; out[4*s2 + r]
#pragma unroll
  for (int r = 0; r < 4; ++r) {
    float2 u0 = s[4 * r], u1 = s[4 * r + 1], u2 = s[4 * r + 2], u3 = s[4 * r + 3];
    float2 e0 = make_float2(u0.x + u2.x, u0.y + u2.y);
    float2 e1 = make_float2(u0.x - u2.x, u0.y - u2.y);
    float2 o0 = make_float2(u1.x + u3.x, u1.y + u3.y);
    float2 o1 = make_float2(u1.x - u3.x, u1.y - u3.y);
    v[r]      = make_float2(e0.x + o0.x, e0.y + o0.y);   // s2=0
    v[4 + r]  = make_float2(e1.x + o1.y, e1.y - o1.x);   // s2=1: e1 - i*o1
    v[8 + r]  = make_float2(e0.x - o0.x, e0.y - o0.y);   // s2=2
    v[12 + r] = make_float2(e1.x - o1.y, e1.y + o1.x);   // s2=3: e1 + i*o1
  }
}

// ---- Pass 1: pack Z = X + iY, radix-4 DIF FFT along z, Hermitian unpack (unchanged) ----
__global__ __launch_bounds__(256) void fft_z_pack(const float* __restrict__ X,
                                                  const float* __restrict__ Y,
                                                  float2* __restrict__ Gx,
                                                  float2* __restrict__ Gy,
                                                  const float2* __restrict__ gtw) {
  __shared__ float zr[256 * 17], zi[256 * 17];   // [slot*17 + line]
  __shared__ float twr[256], twi[256];
  int t = threadIdx.x;
  { float2 w = gtw[t]; twr[t] = w.x; twi[t] = w.y; }
  int li = t >> 4, c = t & 15;
  int y = blockIdx.x >> 4;
  int x0 = (blockIdx.x & 15) << 4;
  const float4* xp = (const float4*)(X + (((size_t)(x0 + li)) << 16) + ((size_t)y << 8));
  const float4* yp = (const float4*)(Y + (((size_t)(x0 + li)) << 16) + ((size_t)y << 8));
#pragma unroll
  for (int it = 0; it < 4; ++it) {
    int e4 = c + 16 * it;
    float4 a = xp[e4];
    float4 b = yp[e4];
    int e = e4 << 2;
    zr[(e + 0) * 17 + li] = a.x; zi[(e + 0) * 17 + li] = b.x;
    zr[(e + 1) * 17 + li] = a.y; zi[(e + 1) * 17 + li] = b.y;
    zr[(e + 2) * 17 + li] = a.z; zi[(e + 2) * 17 + li] = b.z;
    zr[(e + 3) * 17 + li] = a.w; zi[(e + 3) * 17 + li] = b.w;
  }
  __syncthreads();
#pragma unroll
  for (int s = 0; s < 4; ++s) {
    int M = 64 >> (2 * s);
    int F = 1 << (2 * s);
#pragma unroll
    for (int ib = 0; ib < 4; ++ib) {
      int j = c + 16 * ib;
      int p = j & (M - 1);
      int jb = j >> (6 - 2 * s);
      int base = jb * (M << 2) + p;
      bfly4_dif(zr, zi, twr, twi, base * 17 + li, (base + M) * 17 + li,
                (base + 2 * M) * 17 + li, (base + 3 * M) * 17 + li,
                (p * F) & 255, (2 * p * F) & 255, (3 * p * F) & 255);
    }
    __syncthreads();
  }
  int krow = t >> 4, xi = t & 15;
#pragma unroll
  for (int g = 0; g < 9; ++g) {
    int kz = g * 16 + krow;
    if (kz <= 128) {
      int s1 = rev4(kz & 255);
      int s2 = rev4((256 - kz) & 255);
      float ar = zr[s1 * 17 + xi], ai = zi[s1 * 17 + xi];
      float br = zr[s2 * 17 + xi], bi = zi[s2 * 17 + xi];
      size_t off = ((size_t)kz << 16) + ((size_t)y << 8) + (size_t)(x0 + xi);
      Gx[off] = make_float2(0.5f * (ar + br), 0.5f * (ai - bi));
      Gy[off] = make_float2(0.5f * (ai + bi), 0.5f * (br - ar));
    }
  }
}

// ---- Pass 2: y-FFT, four-step 16x16 register FFT; writes rows in NATURAL ky order ----
__global__ __launch_bounds__(256, 4) void fft_y(float2* __restrict__ G,
                                                const float2* __restrict__ gtw) {
  __shared__ float2 scr[16 * 273];   // per-column 273-f2 stride kills bank conflicts
  int t = threadIdx.x;
  int xi = t & 15, h = t >> 4;       // xi: column in tile, h: j mod 16 (then k1)
  int x0 = blockIdx.x << 4;
  int kz = blockIdx.y;
  float2* Gp = G + (size_t)blockIdx.z * VSTRIDE + ((size_t)kz << 16) + (size_t)(x0 + xi);
  float2 v[16];
#pragma unroll
  for (int m = 0; m < 16; ++m) v[m] = Gp[(size_t)((m << 4) | h) << 8];
  fft16(v);                          // v[k1] = Y_h[k1]
#pragma unroll
  for (int k1 = 1; k1 < 16; ++k1) v[k1] = cmul(v[k1], gtw[h * k1]);
  int wb = xi * 273 + h * 17;
#pragma unroll
  for (int k1 = 0; k1 < 16; ++k1) scr[wb + k1] = v[k1];
  __syncthreads();                   // h spans waves -> one block barrier
  float2 u[16];
  int rb = xi * 273 + h;
#pragma unroll
  for (int j2 = 0; j2 < 16; ++j2) u[j2] = scr[rb + j2 * 17];
  fft16(u);                          // u[k2] = X[16*k2 + h]
#pragma unroll
  for (int k2 = 0; k2 < 16; ++k2) Gp[(size_t)((k2 << 4) | h) << 8] = u[k2];
}

// ---- Pass 3: x-FFT (register four-step) + paired products + segmented reduce ----
__global__ __launch_bounds__(256, 4) void fft_x_reduce(const float2* __restrict__ G,
                                                       double* __restrict__ sums,
                                                       const float2* __restrict__ gtw) {
  // pool serves two roles separated by a barrier:
  //  - exchange scratch: 16 contexts (vol,g) * 280 f2, wave-internal (no barrier)
  //  - A arrays: Ax = pool[0..2335], Ay = pool[2336..4671], addr = kx*9 + (kx>>4) + g
  __shared__ float2 pool[4672];
  __shared__ float sh[3 * SBINS];
  int t = threadIdx.x;
  for (int i = t; i < 3 * SBINS; i += 256) sh[i] = 0.f;
  int vol = t >> 7, tt = t & 127;
  int g = tt >> 4, c = tt & 15;      // g: row in tile (0..7), c: j mod 16 (then k1)
  int kz = blockIdx.y;
  int r0 = blockIdx.x << 3;
  const float2* Gp = G + (size_t)vol * VSTRIDE + ((size_t)kz << 16) + ((size_t)(r0 + g) << 8);
  float2 v[16];
#pragma unroll
  for (int m = 0; m < 16; ++m) v[m] = Gp[(m << 4) | c];
  fft16(v);
#pragma unroll
  for (int k1 = 1; k1 < 16; ++k1) v[k1] = cmul(v[k1], gtw[c * k1]);
  {
    int sbase = ((vol << 3) | g) * 280;      // 16-lane context: wave-internal exchange
#pragma unroll
    for (int k1 = 0; k1 < 16; ++k1) pool[sbase + c * 17 + k1] = v[k1];
    float2 u[16];
#pragma unroll
    for (int j2 = 0; j2 < 16; ++j2) u[j2] = pool[sbase + j2 * 17 + c];
    fft16(u);                                // u[k2] = X[16*k2 + c]
    __syncthreads();                         // scratch -> A repurposing fence
    float2* A = pool + vol * 2336;
#pragma unroll
    for (int k2 = 0; k2 < 16; ++k2) {
      int kx = (k2 << 4) | c;
      A[kx * 9 + k2 + g] = u[k2];            // apos(kx,g); kx>>4 == k2
    }
  }
  __syncthreads();
  int fz = kz - ((kz & 128) ? 256 : 0);
  int fz2 = fz * fz;
  int w = t >> 6, l = t & 63;
  const float2* Ax = pool;
  const float2* Ay = pool + 2336;
#pragma unroll
  for (int rr = 0; rr < 2; ++rr) {
    int row = (w << 1) | rr;                 // local row 0..7
    int ky = r0 + row;                       // NATURAL ky (pass 2 writes natural order)
    int fy = ky - ((ky & 128) ? 256 : 0);
    int c2 = fy * fy + fz2;
#pragma unroll
    for (int pass = 0; pass < 2; ++pass) {
      int kx = (pass << 6) | l;
      float2 xv = Ax[kx * 9 + (kx >> 4) + row];
      float2 yv = Ay[kx * 9 + (kx >> 4) + row];
      float nv = xv.x * yv.x + xv.y * yv.y;
      float pv = xv.x * xv.x + xv.y * xv.y;
      float qv = yv.x * yv.x + yv.y * yv.y;
      if (kx != 0) {
        int mk = 256 - kx;
        float2 mx = Ax[mk * 9 + (mk >> 4) + row];
        float2 my = Ay[mk * 9 + (mk >> 4) + row];
        nv += mx.x * my.x + mx.y * my.y;
        pv += mx.x * mx.x + mx.y * mx.y;
        qv += my.x * my.x + my.y * my.y;
      }
      int m = kx * kx + c2;
      int sb = (int)sqrtf((float)m);
      while (sb * sb > m) --sb;
      while ((sb + 1) * (sb + 1) <= m) ++sb;
      seg_flush(sh, sb, nv, pv, qv, l);
    }
    if (l == 0) {                            // kx = 128 (self-mirrored)
      float2 xv = Ax[128 * 9 + 8 + row];
      float2 yv = Ay[128 * 9 + 8 + row];
      int m = 16384 + c2;
      int sb = (int)sqrtf((float)m);
      while (sb * sb > m) --sb;
      while ((sb + 1) * (sb + 1) <= m) ++sb;
      atomicAdd(&sh[3 * sb + 0], xv.x * yv.x + xv.y * yv.y);
      atomicAdd(&sh[3 * sb + 1], xv.x * xv.x + xv.y * xv.y);
      atomicAdd(&sh[3 * sb + 2], yv.x * yv.x + yv.y * yv.y);
    }
  }
  __syncthreads();
  float wf = (kz == 0 || kz == 128) ? 1.f : 2.f;   // kz-plane Hermitian weight
  double* sp = sums + (size_t)(blockIdx.x & (NSPLIT - 1)) * (3 * SBINS);
  for (int i = t; i < 3 * SBINS; i += 256) {
    float vv = sh[i];
    if (vv != 0.f) atomicAdd(&sp[i], (double)(wf * vv));
  }
}

__global__ void finalize(const double* __restrict__ sums, float* __restrict__ out) {
  __shared__ double red[2 * 3 * SBINS];
  int t = threadIdx.x;
  for (int i = t; i < 2 * 3 * SBINS; i += 256) {
    int b = i / (3 * SBINS), k = i - b * (3 * SBINS);
    const double* s = sums + (size_t)b * NSPLIT * 3 * SBINS + k;
    double a = 0.0;
#pragma unroll
    for (int sp = 0; sp < NSPLIT; ++sp) a += s[(size_t)sp * 3 * SBINS];
    red[i] = a;
  }
  __syncthreads();
  if (t == 0) {
    double acc = 0.0;
    for (int b = 0; b < 2; ++b) {
      const double* s = red + b * 3 * SBINS;
      for (int k = 0; k < NSHELL; ++k)
        acc += s[3 * k] / sqrt(s[3 * k + 1] * s[3 * k + 2] + 1e-8);
    }
    out[0] = (float)(acc / (2.0 * (double)NSHELL));
  }
}

extern "C" void kernel_launch(void* const* d_in, const int* in_sizes, int n_in,
                              void* d_out, int out_size, void* d_ws, size_t ws_size,
                              hipStream_t stream) {
  const float* X = (const float*)d_in[0];
  const float* Y = (const float*)d_in[1];
  float2* Gx = (float2*)d_ws;                 // 129 planes
  float2* Gy = Gx + VSTRIDE;                  // 129 planes
  double* sums = (double*)((char*)d_ws + (size_t)2 * VSTRIDE * sizeof(float2));
  float2* gtw = (float2*)(sums + (size_t)2 * NSPLIT * 3 * SBINS);

  hipMemsetAsync(sums, 0, (size_t)2 * NSPLIT * 3 * SBINS * sizeof(double), stream);
  tw_init<<<1, 256, 0, stream>>>(gtw);

  for (int b = 0; b < 2; ++b) {
    fft_z_pack<<<4096, 256, 0, stream>>>(X + (size_t)b * VOL, Y + (size_t)b * VOL, Gx, Gy, gtw);
    fft_y<<<dim3(16, 129, 2), 256, 0, stream>>>(Gx, gtw);
    fft_x_reduce<<<dim3(32, 129), 256, 0, stream>>>(Gx, sums + (size_t)b * NSPLIT * 3 * SBINS, gtw);
  }
  finalize<<<1, 256, 0, stream>>>(sums, (float*)d_out);
}

// Round 2
// 603.610 us; speedup vs baseline: 1.1856x; 1.0124x over previous
//
#include <hip/hip_runtime.h>
#include <math.h>

#define VOL (256 * 256 * 256)
#define NSHELL 222
#define SBINS 224
#define NSPLIT 16
#define PI_D 3.14159265358979323846
#define VSTRIDE ((size_t)129 << 16)   // one half-volume: 129 planes of 256x256 float2

// one-time twiddle table: gtw[k] = exp(-2*pi*i*k/256), f64-accurate
__global__ void tw_init(float2* __restrict__ gtw) {
  int t = threadIdx.x;
  double a = -2.0 * PI_D * (double)t / 256.0;
  gtw[t] = make_float2((float)cos(a), (float)sin(a));
}

// wave-level segmented reduce + flush: bins nondecreasing across lanes.
__device__ __forceinline__ void seg_flush(float* sh, int sb, float nv, float pv,
                                          float qv, int l) {
#pragma unroll
  for (int d = 1; d < 64; d <<= 1) {
    int sbo = __shfl_down(sb, d);
    float no = __shfl_down(nv, d);
    float po = __shfl_down(pv, d);
    float qo = __shfl_down(qv, d);
    if (l + d < 64 && sbo == sb) { nv += no; pv += po; qv += qo; }
  }
  int sbp = __shfl_up(sb, 1);
  if (l == 0 || sbp != sb) {
    atomicAdd(&sh[3 * sb + 0], nv);
    atomicAdd(&sh[3 * sb + 1], pv);
    atomicAdd(&sh[3 * sb + 2], qv);
  }
}

__device__ __forceinline__ float2 cmul(float2 a, float2 b) {
  return make_float2(a.x * b.x - a.y * b.y, a.x * b.y + a.y * b.x);
}

// in-register 16-point DFT, natural-order in and out.
// X[k] = sum_j x[j] * W16^(j*k), W16 = exp(-2*pi*i/16).
__device__ __forceinline__ void fft16(float2* v) {
  const float C1 = 0.92387953251128674f;   // cos(pi/8)
  const float S1 = 0.38268343236508978f;   // sin(pi/8)
  const float R2 = 0.70710678118654752f;   // sqrt(2)/2
  float2 s[16];
  // stage 1: radix-4 over the high input digit; s[4r+p] = B_p[r] * W16^(p*r)
#pragma unroll
  for (int p = 0; p < 4; ++p) {
    float2 a = v[p], b = v[p + 4], cc = v[p + 8], d = v[p + 12];
    float2 t0 = make_float2(a.x + cc.x, a.y + cc.y);
    float2 t2 = make_float2(a.x - cc.x, a.y - cc.y);
    float2 t1 = make_float2(b.x + d.x, b.y + d.y);
    float2 t3 = make_float2(b.x - d.x, b.y - d.y);
    s[p]      = make_float2(t0.x + t1.x, t0.y + t1.y);   // r=0
    s[p + 4]  = make_float2(t2.x + t3.y, t2.y - t3.x);   // r=1: t2 - i*t3
    s[p + 8]  = make_float2(t0.x - t1.x, t0.y - t1.y);   // r=2
    s[p + 12] = make_float2(t2.x - t3.y, t2.y + t3.x);   // r=3: t2 + i*t3
  }
  s[5]  = cmul(s[5],  make_float2(C1, -S1));    // W16^1
  s[6]  = cmul(s[6],  make_float2(R2, -R2));    // W16^2
  s[7]  = cmul(s[7],  make_float2(S1, -C1));    // W16^3
  s[9]  = cmul(s[9],  make_float2(R2, -R2));    // W16^2
  s[10] = cmul(s[10], make_float2(0.f, -1.f));  // W16^4
  s[11] = cmul(s[11], make_float2(-R2, -R2));   // W16^6
  s[13] = cmul(s[13], make_float2(S1, -C1));    // W16^3
  s[14] = cmul(s[14], make_float2(-R2, -R2));   // W16^6
  s[15] = cmul(s[15], make_float2(-C1, S1));    // W16^9
  // stage 2: FFT-4 over p within each group r; out[4*s2 + r]
#pragma unroll
  for (int r = 0; r < 4; ++r) {
    float2 u0 = s[4 * r], u1 = s[4 * r + 1], u2 = s[4 * r + 2], u3 = s[4 * r + 3];
    float2 e0 = make_float2(u0.x + u2.x, u0.y + u2.y);
    float2 e1 = make_float2(u0.x - u2.x, u0.y - u2.y);
    float2 o0 = make_float2(u1.x + u3.x, u1.y + u3.y);
    float2 o1 = make_float2(u1.x - u3.x, u1.y - u3.y);
    v[r]      = make_float2(e0.x + o0.x, e0.y + o0.y);   // s2=0
    v[4 + r]  = make_float2(e1.x + o1.y, e1.y - o1.x);   // s2=1: e1 - i*o1
    v[8 + r]  = make_float2(e0.x - o0.x, e0.y - o0.y);   // s2=2
    v[12 + r] = make_float2(e1.x - o1.y, e1.y + o1.x);   // s2=3: e1 + i*o1
  }
}

// ---- Pass 1: pack Z = X + iY, register four-step FFT along z, Hermitian unpack ----
// Thread (li = t>>4, c = t&15): 16-lane group per x-line, wave-internal exchanges.
// zs[z*17 + li] float2 layout: every access pattern sits at the b64 bank floor.
__global__ __launch_bounds__(256, 4) void fft_z_pack(const float* __restrict__ X,
                                                     const float* __restrict__ Y,
                                                     float2* __restrict__ Gx,
                                                     float2* __restrict__ Gy,
                                                     const float2* __restrict__ gtw) {
  __shared__ float2 zs[256 * 17];    // 34816 B
  int t = threadIdx.x;
  int li = t >> 4, c = t & 15;
  int y = blockIdx.x >> 4;
  int x0 = (blockIdx.x & 15) << 4;
  const float4* xp = (const float4*)(X + (((size_t)(x0 + li)) << 16) + ((size_t)y << 8));
  const float4* yp = (const float4*)(Y + (((size_t)(x0 + li)) << 16) + ((size_t)y << 8));
  // Phase A: coalesced load, stage Z = X + iY as zs[z][li] (group owns line li -> no barrier)
#pragma unroll
  for (int it = 0; it < 4; ++it) {
    float4 a = xp[c + 16 * it];
    float4 b = yp[c + 16 * it];
    int z0 = 4 * c + 64 * it;
    zs[(z0 + 0) * 17 + li] = make_float2(a.x, b.x);
    zs[(z0 + 1) * 17 + li] = make_float2(a.y, b.y);
    zs[(z0 + 2) * 17 + li] = make_float2(a.z, b.z);
    zs[(z0 + 3) * 17 + li] = make_float2(a.w, b.w);
  }
  // Phase B: strided gather v[j1] = z[16*j1 + c], FFT over j1 -> k1, twiddle W256^(c*k1)
  float2 v[16];
#pragma unroll
  for (int m = 0; m < 16; ++m) v[m] = zs[(16 * m + c) * 17 + li];
  fft16(v);
#pragma unroll
  for (int k1 = 1; k1 < 16; ++k1) v[k1] = cmul(v[k1], gtw[c * k1]);
  // Phase C: wave-internal 16x16 transpose (rotated slots keep the bank floor)
#pragma unroll
  for (int k1 = 0; k1 < 16; ++k1) zs[(16 * c + ((k1 + c) & 15)) * 17 + li] = v[k1];
  float2 u[16];
#pragma unroll
  for (int j2 = 0; j2 < 16; ++j2) u[j2] = zs[(16 * j2 + ((c + j2) & 15)) * 17 + li];
  fft16(u);                           // u[k2] = Z[16*k2 + c] of line li, natural order
  // Phase D: re-stage full spectrum in natural kz order
#pragma unroll
  for (int k2 = 0; k2 < 16; ++k2) zs[(16 * k2 + c) * 17 + li] = u[k2];
  __syncthreads();                    // the only barrier: unpack crosses waves
  // Phase E: Hermitian unpack; lanes vary x for coalesced global writes
  int xo = t & 15, ko = t >> 4;
  float2* gx = Gx + ((size_t)y << 8) + (size_t)(x0 + xo);
  float2* gy = Gy + ((size_t)y << 8) + (size_t)(x0 + xo);
#pragma unroll
  for (int g = 0; g < 9; ++g) {
    int kz = 16 * g + ko;
    if (kz <= 128) {
      float2 a = zs[kz * 17 + xo];
      float2 b = zs[((256 - kz) & 255) * 17 + xo];
      size_t off = (size_t)kz << 16;
      gx[off] = make_float2(0.5f * (a.x + b.x), 0.5f * (a.y - b.y));
      gy[off] = make_float2(0.5f * (a.y + b.y), 0.5f * (b.x - a.x));
    }
  }
}

// ---- Pass 2: y-FFT, four-step 16x16 register FFT; writes rows in NATURAL ky order ----
__global__ __launch_bounds__(256, 4) void fft_y(float2* __restrict__ G,
                                                const float2* __restrict__ gtw) {
  __shared__ float2 scr[16 * 273];   // per-column 273-f2 stride kills bank conflicts
  int t = threadIdx.x;
  int xi = t & 15, h = t >> 4;       // xi: column in tile, h: j mod 16 (then k1)
  int x0 = blockIdx.x << 4;
  int kz = blockIdx.y;
  float2* Gp = G + (size_t)blockIdx.z * VSTRIDE + ((size_t)kz << 16) + (size_t)(x0 + xi);
  float2 v[16];
#pragma unroll
  for (int m = 0; m < 16; ++m) v[m] = Gp[(size_t)((m << 4) | h) << 8];
  fft16(v);                          // v[k1] = Y_h[k1]
#pragma unroll
  for (int k1 = 1; k1 < 16; ++k1) v[k1] = cmul(v[k1], gtw[h * k1]);
  int wb = xi * 273 + h * 17;
#pragma unroll
  for (int k1 = 0; k1 < 16; ++k1) scr[wb + k1] = v[k1];
  __syncthreads();                   // h spans waves -> one block barrier
  float2 u[16];
  int rb = xi * 273 + h;
#pragma unroll
  for (int j2 = 0; j2 < 16; ++j2) u[j2] = scr[rb + j2 * 17];
  fft16(u);                          // u[k2] = X[16*k2 + h]
#pragma unroll
  for (int k2 = 0; k2 < 16; ++k2) Gp[(size_t)((k2 << 4) | h) << 8] = u[k2];
}

// ---- Pass 3: x-FFT (register four-step) + paired products + segmented reduce ----
__global__ __launch_bounds__(256, 4) void fft_x_reduce(const float2* __restrict__ G,
                                                       double* __restrict__ sums,
                                                       const float2* __restrict__ gtw) {
  // pool serves two roles separated by a barrier:
  //  - exchange scratch: 16 contexts (vol,g) * 280 f2, wave-internal (no barrier)
  //  - A arrays: Ax = pool[0..2335], Ay = pool[2336..4671], addr = kx*9 + (kx>>4) + g
  __shared__ float2 pool[4672];
  __shared__ float sh[3 * SBINS];
  int t = threadIdx.x;
  for (int i = t; i < 3 * SBINS; i += 256) sh[i] = 0.f;
  int vol = t >> 7, tt = t & 127;
  int g = tt >> 4, c = tt & 15;      // g: row in tile (0..7), c: j mod 16 (then k1)
  int kz = blockIdx.y;
  int r0 = blockIdx.x << 3;
  const float2* Gp = G + (size_t)vol * VSTRIDE + ((size_t)kz << 16) + ((size_t)(r0 + g) << 8);
  float2 v[16];
#pragma unroll
  for (int m = 0; m < 16; ++m) v[m] = Gp[(m << 4) | c];
  fft16(v);
#pragma unroll
  for (int k1 = 1; k1 < 16; ++k1) v[k1] = cmul(v[k1], gtw[c * k1]);
  {
    int sbase = ((vol << 3) | g) * 280;      // 16-lane context: wave-internal exchange
#pragma unroll
    for (int k1 = 0; k1 < 16; ++k1) pool[sbase + c * 17 + k1] = v[k1];
    float2 u[16];
#pragma unroll
    for (int j2 = 0; j2 < 16; ++j2) u[j2] = pool[sbase + j2 * 17 + c];
    fft16(u);                                // u[k2] = X[16*k2 + c]
    __syncthreads();                         // scratch -> A repurposing fence
    float2* A = pool + vol * 2336;
#pragma unroll
    for (int k2 = 0; k2 < 16; ++k2) {
      int kx = (k2 << 4) | c;
      A[kx * 9 + k2 + g] = u[k2];            // apos(kx,g); kx>>4 == k2
    }
  }
  __syncthreads();
  int fz = kz - ((kz & 128) ? 256 : 0);
  int fz2 = fz * fz;
  int w = t >> 6, l = t & 63;
  const float2* Ax = pool;
  const float2* Ay = pool + 2336;
#pragma unroll
  for (int rr = 0; rr < 2; ++rr) {
    int row = (w << 1) | rr;                 // local row 0..7
    int ky = r0 + row;                       // NATURAL ky (pass 2 writes natural order)
    int fy = ky - ((ky & 128) ? 256 : 0);
    int c2 = fy * fy + fz2;
#pragma unroll
    for (int pass = 0; pass < 2; ++pass) {
      int kx = (pass << 6) | l;
      float2 xv = Ax[kx * 9 + (kx >> 4) + row];
      float2 yv = Ay[kx * 9 + (kx >> 4) + row];
      float nv = xv.x * yv.x + xv.y * yv.y;
      float pv = xv.x * xv.x + xv.y * xv.y;
      float qv = yv.x * yv.x + yv.y * yv.y;
      if (kx != 0) {
        int mk = 256 - kx;
        float2 mx = Ax[mk * 9 + (mk >> 4) + row];
        float2 my = Ay[mk * 9 + (mk >> 4) + row];
        nv += mx.x * my.x + mx.y * my.y;
        pv += mx.x * mx.x + mx.y * mx.y;
        qv += my.x * my.x + my.y * my.y;
      }
      int m = kx * kx + c2;
      int sb = (int)sqrtf((float)m);
      while (sb * sb > m) --sb;
      while ((sb + 1) * (sb + 1) <= m) ++sb;
      seg_flush(sh, sb, nv, pv, qv, l);
    }
    if (l == 0) {                            // kx = 128 (self-mirrored)
      float2 xv = Ax[128 * 9 + 8 + row];
      float2 yv = Ay[128 * 9 + 8 + row];
      int m = 16384 + c2;
      int sb = (int)sqrtf((float)m);
      while (sb * sb > m) --sb;
      while ((sb + 1) * (sb + 1) <= m) ++sb;
      atomicAdd(&sh[3 * sb + 0], xv.x * yv.x + xv.y * yv.y);
      atomicAdd(&sh[3 * sb + 1], xv.x * xv.x + xv.y * xv.y);
      atomicAdd(&sh[3 * sb + 2], yv.x * yv.x + yv.y * yv.y);
    }
  }
  __syncthreads();
  float wf = (kz == 0 || kz == 128) ? 1.f : 2.f;   // kz-plane Hermitian weight
  double* sp = sums + (size_t)(blockIdx.x & (NSPLIT - 1)) * (3 * SBINS);
  for (int i = t; i < 3 * SBINS; i += 256) {
    float vv = sh[i];
    if (vv != 0.f) atomicAdd(&sp[i], (double)(wf * vv));
  }
}

__global__ void finalize(const double* __restrict__ sums, float* __restrict__ out) {
  __shared__ double red[2 * 3 * SBINS];
  int t = threadIdx.x;
  for (int i = t; i < 2 * 3 * SBINS; i += 256) {
    int b = i / (3 * SBINS), k = i - b * (3 * SBINS);
    const double* s = sums + (size_t)b * NSPLIT * 3 * SBINS + k;
    double a = 0.0;
#pragma unroll
    for (int sp = 0; sp < NSPLIT; ++sp) a += s[(size_t)sp * 3 * SBINS];
    red[i] = a;
  }
  __syncthreads();
  if (t == 0) {
    double acc = 0.0;
    for (int b = 0; b < 2; ++b) {
      const double* s = red + b * 3 * SBINS;
      for (int k = 0; k < NSHELL; ++k)
        acc += s[3 * k] / sqrt(s[3 * k + 1] * s[3 * k + 2] + 1e-8);
    }
    out[0] = (float)(acc / (2.0 * (double)NSHELL));
  }
}

extern "C" void kernel_launch(void* const* d_in, const int* in_sizes, int n_in,
                              void* d_out, int out_size, void* d_ws, size_t ws_size,
                              hipStream_t stream) {
  const float* X = (const float*)d_in[0];
  const float* Y = (const float*)d_in[1];
  float2* Gx = (float2*)d_ws;                 // 129 planes
  float2* Gy = Gx + VSTRIDE;                  // 129 planes
  double* sums = (double*)((char*)d_ws + (size_t)2 * VSTRIDE * sizeof(float2));
  float2* gtw = (float2*)(sums + (size_t)2 * NSPLIT * 3 * SBINS);

  hipMemsetAsync(sums, 0, (size_t)2 * NSPLIT * 3 * SBINS * sizeof(double), stream);
  tw_init<<<1, 256, 0, stream>>>(gtw);

  for (int b = 0; b < 2; ++b) {
    fft_z_pack<<<4096, 256, 0, stream>>>(X + (size_t)b * VOL, Y + (size_t)b * VOL, Gx, Gy, gtw);
    fft_y<<<dim3(16, 129, 2), 256, 0, stream>>>(Gx, gtw);
    fft_x_reduce<<<dim3(32, 129), 256, 0, stream>>>(Gx, sums + (size_t)b * NSPLIT * 3 * SBINS, gtw);
  }
  finalize<<<1, 256, 0, stream>>>(sums, (float*)d_out);
}